// Round 4
// baseline (302.343 us; speedup 1.0000x reference)
//
#include <hip/hip_runtime.h>

#define DM 256
#define SEQ 4096

typedef __attribute__((ext_vector_type(8))) short bf16x8;
typedef __attribute__((ext_vector_type(4))) float f32x4;

#define MFMA16(a, b, c) __builtin_amdgcn_mfma_f32_16x16x32_bf16(a, b, c, 0, 0, 0)

__device__ __forceinline__ short f2bf(float f) {
    union { float f; unsigned u; } c; c.f = f;
    unsigned r = (c.u + 0x7FFFu + ((c.u >> 16) & 1u)) >> 16;   // RNE
    return (short)r;
}
__device__ __forceinline__ float bf2f(short s) {
    union { unsigned u; float f; } c; c.u = ((unsigned)(unsigned short)s) << 16; return c.f;
}
__device__ __forceinline__ bf16x8 pack8(float4 a, float4 b) {
    bf16x8 r;
    r[0] = f2bf(a.x); r[1] = f2bf(a.y); r[2] = f2bf(a.z); r[3] = f2bf(a.w);
    r[4] = f2bf(b.x); r[5] = f2bf(b.y); r[6] = f2bf(b.z); r[7] = f2bf(b.w);
    return r;
}

// ---------------- weight f32 -> bf16 ----------------
// ws shorts: wq@0 wk@65536 wv@131072 wm@196608 w1@262144 w2@393216
__global__ __launch_bounds__(256) void kWconv(const float* __restrict__ wq, const float* __restrict__ wk,
                                              const float* __restrict__ wv, const float* __restrict__ wm,
                                              const float* __restrict__ w1, const float* __restrict__ w2,
                                              short* __restrict__ dstws) {
    int blk = blockIdx.x;
    const float* src; short* dst;
    if (blk < 32)       { src = wq; dst = dstws;          }
    else if (blk < 64)  { src = wk; dst = dstws + 65536;  blk -= 32; }
    else if (blk < 96)  { src = wv; dst = dstws + 131072; blk -= 64; }
    else if (blk < 128) { src = wm; dst = dstws + 196608; blk -= 96; }
    else if (blk < 192) { src = w1; dst = dstws + 262144; blk -= 128; }
    else                { src = w2; dst = dstws + 393216; blk -= 192; }
    int idx = (blk * 256 + threadIdx.x) * 8;
    float4 f0 = *(const float4*)(src + idx), f1 = *(const float4*)(src + idx + 4);
    *(bf16x8*)(dst + idx) = pack8(f0, f1);
}

// ---------------- kernel A: K/V proj + per-block KV/Ksum partials ----------------
// grid 1024 = 8 b x 128 blocks (32 src rows). 512 thr = 8 waves; wave w = head w.
// LDS 32KB -> 4 blocks/CU resident (grid exactly fills device).
__global__ __launch_bounds__(512, 8) void kA(const float* __restrict__ src,
                                             const short* __restrict__ wk, const short* __restrict__ wv,
                                             short* __restrict__ kv_part, float* __restrict__ ksum_part) {
    __shared__ char lds[32768];   // phase1: xs[32][256] bf16 swz (16KB); phase3: per-wave kT/vT 4KB x8
    int t = threadIdx.x, lane = t & 63, w = t >> 6, r16 = lane & 15, g = lane >> 4;
    int b = blockIdx.x >> 7, blk = blockIdx.x & 127;
    const float* S = src + ((size_t)b * SEQ + blk * 32) * DM;
#pragma unroll
    for (int i = 0; i < 2; i++) {
        int chunk = t + i * 512, row = chunk >> 5, c8 = chunk & 31;
        const float* p = S + row * DM + c8 * 8;
        float4 f0 = *(const float4*)p, f1 = *(const float4*)(p + 4);
        int by = (row * 512 + c8 * 16) ^ ((row & 7) << 4);
        *(bf16x8*)(lds + by) = pack8(f0, f1);
    }
    __syncthreads();
    f32x4 zz = {0.f, 0.f, 0.f, 0.f};
    f32x4 ak[2][2], av[2][2];
#pragma unroll
    for (int mi = 0; mi < 2; mi++)
#pragma unroll
        for (int ni = 0; ni < 2; ni++) { ak[mi][ni] = zz; av[mi][ni] = zz; }
#pragma unroll
    for (int kt = 0; kt < 8; kt++) {
        bf16x8 A[2];
#pragma unroll
        for (int mi = 0; mi < 2; mi++) {
            int row = mi * 16 + r16;
            A[mi] = *(const bf16x8*)(lds + ((row * 512 + (kt * 32 + g * 8) * 2) ^ ((row & 7) << 4)));
        }
#pragma unroll
        for (int ni = 0; ni < 2; ni++) {
            int n = w * 32 + ni * 16 + r16;
            bf16x8 Bk = *(const bf16x8*)(wk + n * DM + kt * 32 + g * 8);
            bf16x8 Bv = *(const bf16x8*)(wv + n * DM + kt * 32 + g * 8);
#pragma unroll
            for (int mi = 0; mi < 2; mi++) {
                ak[mi][ni] = MFMA16(A[mi], Bk, ak[mi][ni]);
                av[mi][ni] = MFMA16(A[mi], Bv, av[mi][ni]);
            }
        }
    }
    __syncthreads();   // xs reads done before kT/vT overwrite
    // elu(k)+1, ksum partials, per-wave transposed tiles kT/vT [32 feat][32 s]
    char* kT = lds + w * 4096;
    char* vT = kT + 2048;
    float ksp[2] = {0.f, 0.f};
#pragma unroll
    for (int mi = 0; mi < 2; mi++)
#pragma unroll
        for (int ni = 0; ni < 2; ni++)
#pragma unroll
            for (int j = 0; j < 4; j++) {
                float q = ak[mi][ni][j];
                float e = q > 0.f ? q + 1.f : __expf(q);
                ksp[ni] += e;
                int srow = mi * 16 + g * 4 + j, feat = ni * 16 + r16;
                int by = feat * 64 + srow * 2;
                *(short*)(kT + by) = f2bf(e);
                *(short*)(vT + by) = f2bf(av[mi][ni][j]);
            }
    __syncthreads();
    // KVT[v][d] = sum_s V[s][v] * K[s][d]  (per wave, own head; K-dim = 32 = one MFMA)
    f32x4 kv[2][2];
#pragma unroll
    for (int vi = 0; vi < 2; vi++)
#pragma unroll
        for (int di = 0; di < 2; di++) kv[vi][di] = zz;
    {
        bf16x8 Af[2], Bf[2];
#pragma unroll
        for (int vi = 0; vi < 2; vi++) {
            int row = vi * 16 + r16;
            Af[vi] = *(const bf16x8*)(vT + row * 64 + g * 16);
            Bf[vi] = *(const bf16x8*)(kT + row * 64 + g * 16);
        }
#pragma unroll
        for (int vi = 0; vi < 2; vi++)
#pragma unroll
            for (int di = 0; di < 2; di++) kv[vi][di] = MFMA16(Af[vi], Bf[di], kv[vi][di]);
    }
    short* kvp = kv_part + ((size_t)(b * 128 + blk) * 8 + w) * 1024;
#pragma unroll
    for (int vi = 0; vi < 2; vi++)
#pragma unroll
        for (int di = 0; di < 2; di++)
#pragma unroll
            for (int j = 0; j < 4; j++) {
                int v = vi * 16 + g * 4 + j, d = di * 16 + r16;
                kvp[v * 32 + d] = f2bf(kv[vi][di][j]);
            }
#pragma unroll
    for (int ni = 0; ni < 2; ni++) {
        ksp[ni] += __shfl_xor(ksp[ni], 16);
        ksp[ni] += __shfl_xor(ksp[ni], 32);
    }
    if (lane < 16) {
        float* kp = ksum_part + (size_t)(b * 128 + blk) * 256 + w * 32;
#pragma unroll
        for (int ni = 0; ni < 2; ni++) kp[ni * 16 + lane] = ksp[ni];
    }
}

// ---------------- kernel A2: reduce partials ----------------
// grid 256 = b(8) x h(8) x quarter(4), 256 thr. ksum reduced 4-way parallel into ksum4.
__global__ __launch_bounds__(256) void kA2(const short* __restrict__ kv_part, const float* __restrict__ ksum_part,
                                           short* __restrict__ kvt_bf, float* __restrict__ ksum4) {
    int blk = blockIdx.x, t = threadIdx.x;
    int b = blk >> 5, h = (blk >> 2) & 7, q = blk & 3;
    int e = q * 256 + t;
    float s0 = 0.f, s1 = 0.f, s2 = 0.f, s3 = 0.f;
    for (int bk = 0; bk < 128; bk += 4) {
        s0 += bf2f(kv_part[((size_t)(b * 128 + bk) * 8 + h) * 1024 + e]);
        s1 += bf2f(kv_part[((size_t)(b * 128 + bk + 1) * 8 + h) * 1024 + e]);
        s2 += bf2f(kv_part[((size_t)(b * 128 + bk + 2) * 8 + h) * 1024 + e]);
        s3 += bf2f(kv_part[((size_t)(b * 128 + bk + 3) * 8 + h) * 1024 + e]);
    }
    kvt_bf[(size_t)(b * 8 + h) * 1024 + e] = f2bf((s0 + s1) + (s2 + s3));
    if (t < 32) {
        float s = 0.f;
        for (int bk = q * 32; bk < q * 32 + 32; bk++)
            s += ksum_part[(size_t)(b * 128 + bk) * 256 + h * 32 + t];
        ksum4[((b * 8 + h) * 4 + q) * 32 + t] = s;
    }
}

// ---------------- kernel BC: Q proj + attend + merge + LN1 + MLP + LN2 ----------------
// grid 1024 = 8 b x 128 blocks (32 rows). 512 thr = 8 waves. LDS 35KB -> 4 blocks/CU.
__global__ __launch_bounds__(512, 8) void kBC(const float* __restrict__ x,
                                              const short* __restrict__ wq_bf, const short* __restrict__ wm_bf,
                                              const short* __restrict__ w1_bf, const short* __restrict__ w2_bf,
                                              const short* __restrict__ kvt_bf, const float* __restrict__ ksum4,
                                              const float* __restrict__ g1, const float* __restrict__ b1,
                                              const float* __restrict__ g2, const float* __restrict__ b2,
                                              float* __restrict__ out) {
    __shared__ char lds[35840];
    // xt@0: [32][256] bf16 swz (16KB) -- x, later x1
    // qa@16384: [32][256] bf16 swz (16KB) -- Q, attended, then h-halves
    // red@32768: [32][8][2] f32 (2KB); ksl@34816: [256] f32 (1KB)
    char* xt = lds;
    char* qa = lds + 16384;
    float* red = (float*)(lds + 32768);
    float* ksl = (float*)(lds + 34816);
    int t = threadIdx.x, lane = t & 63, w = t >> 6, r16 = lane & 15, g = lane >> 4;
    int b = blockIdx.x >> 7, lb = blockIdx.x & 127, l0 = lb * 32;
    const float* xb = x + ((size_t)b * SEQ + l0) * DM;
#pragma unroll
    for (int i = 0; i < 2; i++) {
        int chunk = t + i * 512, row = chunk >> 5, c8 = chunk & 31;
        const float* p = xb + row * DM + c8 * 8;
        float4 f0 = *(const float4*)p, f1 = *(const float4*)(p + 4);
        int by = (row * 512 + c8 * 16) ^ ((row & 7) << 4);
        *(bf16x8*)(xt + by) = pack8(f0, f1);
    }
    if (t < 256) {
        int h = t >> 5, d = t & 31;
        const float* kp = ksum4 + (size_t)((b * 8 + h) * 4) * 32 + d;
        ksl[t] = (kp[0] + kp[32]) + (kp[64] + kp[96]);
    }
    __syncthreads();
    f32x4 zz = {0.f, 0.f, 0.f, 0.f};
    // ---- Q projection (wave w -> head w's 32 cols) ----
    f32x4 acc[2][2];
#pragma unroll
    for (int mi = 0; mi < 2; mi++)
#pragma unroll
        for (int ni = 0; ni < 2; ni++) acc[mi][ni] = zz;
#pragma unroll
    for (int kt = 0; kt < 8; kt++) {
        bf16x8 A[2], Bf[2];
#pragma unroll
        for (int mi = 0; mi < 2; mi++) {
            int row = mi * 16 + r16;
            A[mi] = *(const bf16x8*)(xt + ((row * 512 + (kt * 32 + g * 8) * 2) ^ ((row & 7) << 4)));
        }
#pragma unroll
        for (int ni = 0; ni < 2; ni++)
            Bf[ni] = *(const bf16x8*)(wq_bf + (w * 32 + ni * 16 + r16) * DM + kt * 32 + g * 8);
#pragma unroll
        for (int mi = 0; mi < 2; mi++)
#pragma unroll
            for (int ni = 0; ni < 2; ni++) acc[mi][ni] = MFMA16(A[mi], Bf[ni], acc[mi][ni]);
    }
    // elu+1 and Z denominators
    float ks0 = ksl[w * 32 + r16], ks1 = ksl[w * 32 + 16 + r16];
    float Zr[2][4];
#pragma unroll
    for (int mi = 0; mi < 2; mi++)
#pragma unroll
        for (int j = 0; j < 4; j++) {
#pragma unroll
            for (int ni = 0; ni < 2; ni++) {
                float q = acc[mi][ni][j];
                acc[mi][ni][j] = q > 0.f ? q + 1.f : __expf(q);
            }
            float d0 = acc[mi][0][j] * ks0 + acc[mi][1][j] * ks1;
#pragma unroll
            for (int m = 1; m < 16; m <<= 1) d0 += __shfl_xor(d0, m);
            Zr[mi][j] = 1.f / (d0 + 1e-6f);
        }
    // write Q (bf16 swz, wave-private cols)
#pragma unroll
    for (int mi = 0; mi < 2; mi++)
#pragma unroll
        for (int ni = 0; ni < 2; ni++)
#pragma unroll
            for (int j = 0; j < 4; j++) {
                int row = mi * 16 + g * 4 + j, col = w * 32 + ni * 16 + r16;
                *(short*)(qa + ((row * 512 + col * 2) ^ ((row & 7) << 4))) = f2bf(acc[mi][ni][j]);
            }
    // ---- attend (wave-private cols, K-dim=32) ----
    f32x4 at[2][2];
#pragma unroll
    for (int mi = 0; mi < 2; mi++)
#pragma unroll
        for (int vi = 0; vi < 2; vi++) at[mi][vi] = zz;
    {
        bf16x8 A2[2], B2[2];
#pragma unroll
        for (int mi = 0; mi < 2; mi++) {
            int row = mi * 16 + r16, col = w * 32 + g * 8;
            A2[mi] = *(const bf16x8*)(qa + ((row * 512 + col * 2) ^ ((row & 7) << 4)));
        }
        const short* kvb = kvt_bf + (size_t)(b * 8 + w) * 1024;
#pragma unroll
        for (int vi = 0; vi < 2; vi++)
            B2[vi] = *(const bf16x8*)(kvb + (vi * 16 + r16) * 32 + g * 8);
#pragma unroll
        for (int mi = 0; mi < 2; mi++)
#pragma unroll
            for (int vi = 0; vi < 2; vi++) at[mi][vi] = MFMA16(A2[mi], B2[vi], at[mi][vi]);
    }
    // scale by Z, overwrite qa with attended (wave-private cols)
#pragma unroll
    for (int mi = 0; mi < 2; mi++)
#pragma unroll
        for (int vi = 0; vi < 2; vi++)
#pragma unroll
            for (int j = 0; j < 4; j++) {
                int row = mi * 16 + g * 4 + j, col = w * 32 + vi * 16 + r16;
                *(short*)(qa + ((row * 512 + col * 2) ^ ((row & 7) << 4))) = f2bf(at[mi][vi][j] * Zr[mi][j]);
            }
    __syncthreads();   // merge reads all columns
    // ---- merge GEMM ----
    f32x4 am[2][2];
#pragma unroll
    for (int mi = 0; mi < 2; mi++)
#pragma unroll
        for (int ni = 0; ni < 2; ni++) am[mi][ni] = zz;
#pragma unroll
    for (int kt = 0; kt < 8; kt++) {
        bf16x8 A[2], Bf[2];
#pragma unroll
        for (int mi = 0; mi < 2; mi++) {
            int row = mi * 16 + r16;
            A[mi] = *(const bf16x8*)(qa + ((row * 512 + (kt * 32 + g * 8) * 2) ^ ((row & 7) << 4)));
        }
#pragma unroll
        for (int ni = 0; ni < 2; ni++)
            Bf[ni] = *(const bf16x8*)(wm_bf + (w * 32 + ni * 16 + r16) * DM + kt * 32 + g * 8);
#pragma unroll
        for (int mi = 0; mi < 2; mi++)
#pragma unroll
            for (int ni = 0; ni < 2; ni++) am[mi][ni] = MFMA16(A[mi], Bf[ni], am[mi][ni]);
    }
    // LN1 partials
#pragma unroll
    for (int mi = 0; mi < 2; mi++)
#pragma unroll
        for (int j = 0; j < 4; j++) {
            float s = am[mi][0][j] + am[mi][1][j];
            float s2 = am[mi][0][j] * am[mi][0][j] + am[mi][1][j] * am[mi][1][j];
#pragma unroll
            for (int m = 1; m < 16; m <<= 1) { s += __shfl_xor(s, m); s2 += __shfl_xor(s2, m); }
            if (r16 == 0) { int row = mi * 16 + g * 4 + j; red[(row * 8 + w) * 2] = s; red[(row * 8 + w) * 2 + 1] = s2; }
        }
    __syncthreads();
    // x1 = x + LN1(message), in place in xt
    {
        float g1v[2], b1v[2];
#pragma unroll
        for (int ni = 0; ni < 2; ni++) { int col = w * 32 + ni * 16 + r16; g1v[ni] = g1[col]; b1v[ni] = b1[col]; }
#pragma unroll
        for (int mi = 0; mi < 2; mi++)
#pragma unroll
            for (int j = 0; j < 4; j++) {
                int row = mi * 16 + g * 4 + j;
                float mu = 0.f, ex2 = 0.f;
#pragma unroll
                for (int ww = 0; ww < 8; ww++) { mu += red[(row * 8 + ww) * 2]; ex2 += red[(row * 8 + ww) * 2 + 1]; }
                mu *= (1.f / DM); ex2 *= (1.f / DM);
                float rstd = rsqrtf(ex2 - mu * mu + 1e-5f);
#pragma unroll
                for (int ni = 0; ni < 2; ni++) {
                    int col = w * 32 + ni * 16 + r16;
                    int by = (row * 512 + col * 2) ^ ((row & 7) << 4);
                    float xv = bf2f(*(const short*)(xt + by));
                    *(short*)(xt + by) = f2bf(xv + (am[mi][ni][j] - mu) * rstd * g1v[ni] + b1v[ni]);
                }
            }
    }
    __syncthreads();
    // ---- MLP fused in 2 halves of h (qa reused as [32][256] h-tile) ----
    f32x4 a2[2][2];
#pragma unroll
    for (int mi = 0; mi < 2; mi++)
#pragma unroll
        for (int ni = 0; ni < 2; ni++) a2[mi][ni] = zz;
#pragma unroll
    for (int hf = 0; hf < 2; hf++) {
        // GEMM1 half: wave w -> h-cols hf*256 + w*32 + [0,32)
        f32x4 a1[2][2];
#pragma unroll
        for (int mi = 0; mi < 2; mi++)
#pragma unroll
            for (int ni = 0; ni < 2; ni++) a1[mi][ni] = zz;
#pragma unroll
        for (int kt = 0; kt < 8; kt++) {
            bf16x8 A[2], Bf[2];
#pragma unroll
            for (int mi = 0; mi < 2; mi++) {
                int row = mi * 16 + r16;
                A[mi] = *(const bf16x8*)(xt + ((row * 512 + (kt * 32 + g * 8) * 2) ^ ((row & 7) << 4)));
            }
#pragma unroll
            for (int ni = 0; ni < 2; ni++)
                Bf[ni] = *(const bf16x8*)(w1_bf + (hf * 256 + w * 32 + ni * 16 + r16) * DM + kt * 32 + g * 8);
#pragma unroll
            for (int mi = 0; mi < 2; mi++)
#pragma unroll
                for (int ni = 0; ni < 2; ni++) a1[mi][ni] = MFMA16(A[mi], Bf[ni], a1[mi][ni]);
        }
        // relu + write h-half (wave-private cols within [0,256))
#pragma unroll
        for (int mi = 0; mi < 2; mi++)
#pragma unroll
            for (int ni = 0; ni < 2; ni++)
#pragma unroll
                for (int j = 0; j < 4; j++) {
                    float hv = a1[mi][ni][j]; hv = hv > 0.f ? hv : 0.f;
                    int row = mi * 16 + g * 4 + j, col = w * 32 + ni * 16 + r16;
                    *(short*)(qa + ((row * 512 + col * 2) ^ ((row & 7) << 4))) = f2bf(hv);
                }
        __syncthreads();
        // GEMM2 partial over this half's K=256
#pragma unroll
        for (int kt = 0; kt < 8; kt++) {
            bf16x8 A[2], Bf[2];
#pragma unroll
            for (int mi = 0; mi < 2; mi++) {
                int row = mi * 16 + r16;
                A[mi] = *(const bf16x8*)(qa + ((row * 512 + (kt * 32 + g * 8) * 2) ^ ((row & 7) << 4)));
            }
#pragma unroll
            for (int ni = 0; ni < 2; ni++)
                Bf[ni] = *(const bf16x8*)(w2_bf + (w * 32 + ni * 16 + r16) * 512 + hf * 256 + kt * 32 + g * 8);
#pragma unroll
            for (int mi = 0; mi < 2; mi++)
#pragma unroll
                for (int ni = 0; ni < 2; ni++) a2[mi][ni] = MFMA16(A[mi], Bf[ni], a2[mi][ni]);
        }
        __syncthreads();
    }
    // LN2 partials
#pragma unroll
    for (int mi = 0; mi < 2; mi++)
#pragma unroll
        for (int j = 0; j < 4; j++) {
            float s = a2[mi][0][j] + a2[mi][1][j];
            float s2 = a2[mi][0][j] * a2[mi][0][j] + a2[mi][1][j] * a2[mi][1][j];
#pragma unroll
            for (int m = 1; m < 16; m <<= 1) { s += __shfl_xor(s, m); s2 += __shfl_xor(s2, m); }
            if (r16 == 0) { int row = mi * 16 + g * 4 + j; red[(row * 8 + w) * 2] = s; red[(row * 8 + w) * 2 + 1] = s2; }
        }
    __syncthreads();
    // out = x1 + LN2(y)
    {
        float g2v[2], b2v[2];
#pragma unroll
        for (int ni = 0; ni < 2; ni++) { int col = w * 32 + ni * 16 + r16; g2v[ni] = g2[col]; b2v[ni] = b2[col]; }
        float* op = out + ((size_t)b * SEQ + l0) * DM;
#pragma unroll
        for (int mi = 0; mi < 2; mi++)
#pragma unroll
            for (int j = 0; j < 4; j++) {
                int row = mi * 16 + g * 4 + j;
                float mu = 0.f, ex2 = 0.f;
#pragma unroll
                for (int ww = 0; ww < 8; ww++) { mu += red[(row * 8 + ww) * 2]; ex2 += red[(row * 8 + ww) * 2 + 1]; }
                mu *= (1.f / DM); ex2 *= (1.f / DM);
                float rstd = rsqrtf(ex2 - mu * mu + 1e-5f);
#pragma unroll
                for (int ni = 0; ni < 2; ni++) {
                    int col = w * 32 + ni * 16 + r16;
                    float xv = bf2f(*(const short*)(xt + ((row * 512 + col * 2) ^ ((row & 7) << 4))));
                    op[row * DM + col] = xv + (a2[mi][ni][j] - mu) * rstd * g2v[ni] + b2v[ni];
                }
            }
    }
}

extern "C" void kernel_launch(void* const* d_in, const int* in_sizes, int n_in,
                              void* d_out, int out_size, void* d_ws, size_t ws_size,
                              hipStream_t stream) {
    const float* x   = (const float*)d_in[0];
    const float* src = (const float*)d_in[1];
    const float* wq  = (const float*)d_in[2];
    const float* wk  = (const float*)d_in[3];
    const float* wv  = (const float*)d_in[4];
    const float* wm  = (const float*)d_in[5];
    const float* w1  = (const float*)d_in[6];
    const float* w2  = (const float*)d_in[7];
    const float* g1  = (const float*)d_in[8];
    const float* b1  = (const float*)d_in[9];
    const float* g2  = (const float*)d_in[10];
    const float* b2  = (const float*)d_in[11];
    float* out = (float*)d_out;

    char* ws = (char*)d_ws;
    short* w_bf      = (short*)ws;                    // 1,048,576 B
    short* kvt_bf    = (short*)(ws + 1048576);        //   131,072 B
    float* ksum4     = (float*)(ws + 1179648);        //    32,768 B
    short* kv_part   = (short*)(ws + 1212416);        // 16,777,216 B (bf16 partials)
    float* ksum_part = (float*)(ws + 17989632);       //  1,048,576 B  -> total 19.0 MB

    kWconv<<<256, 256, 0, stream>>>(wq, wk, wv, wm, w1, w2, w_bf);
    kA<<<1024, 512, 0, stream>>>(src, w_bf + 65536, w_bf + 131072, kv_part, ksum_part);
    kA2<<<256, 256, 0, stream>>>(kv_part, ksum_part, kvt_bf, ksum4);
    kBC<<<1024, 512, 0, stream>>>(x, w_bf, w_bf + 196608, w_bf + 262144, w_bf + 393216,
                                  kvt_bf, ksum4, g1, b1, g2, b2, out);
}

// Round 5
// 258.365 us; speedup vs baseline: 1.1702x; 1.1702x over previous
//
#include <hip/hip_runtime.h>

#define DM 256
#define SEQ 4096

typedef __attribute__((ext_vector_type(8))) short bf16x8;
typedef __attribute__((ext_vector_type(4))) float f32x4;

#define MFMA16(a, b, c) __builtin_amdgcn_mfma_f32_16x16x32_bf16(a, b, c, 0, 0, 0)

__device__ __forceinline__ short f2bf(float f) {
    union { float f; unsigned u; } c; c.f = f;
    unsigned r = (c.u + 0x7FFFu + ((c.u >> 16) & 1u)) >> 16;   // RNE
    return (short)r;
}
__device__ __forceinline__ float bf2f(short s) {
    union { unsigned u; float f; } c; c.u = ((unsigned)(unsigned short)s) << 16; return c.f;
}
__device__ __forceinline__ bf16x8 pack8(float4 a, float4 b) {
    bf16x8 r;
    r[0] = f2bf(a.x); r[1] = f2bf(a.y); r[2] = f2bf(a.z); r[3] = f2bf(a.w);
    r[4] = f2bf(b.x); r[5] = f2bf(b.y); r[6] = f2bf(b.z); r[7] = f2bf(b.w);
    return r;
}

// ---------------- weight f32 -> bf16 ----------------
// ws shorts: wq@0 wk@65536 wv@131072 wm@196608 w1@262144 w2@393216
__global__ __launch_bounds__(256) void kWconv(const float* __restrict__ wq, const float* __restrict__ wk,
                                              const float* __restrict__ wv, const float* __restrict__ wm,
                                              const float* __restrict__ w1, const float* __restrict__ w2,
                                              short* __restrict__ dstws) {
    int blk = blockIdx.x;
    const float* src; short* dst;
    if (blk < 32)       { src = wq; dst = dstws;          }
    else if (blk < 64)  { src = wk; dst = dstws + 65536;  blk -= 32; }
    else if (blk < 96)  { src = wv; dst = dstws + 131072; blk -= 64; }
    else if (blk < 128) { src = wm; dst = dstws + 196608; blk -= 96; }
    else if (blk < 192) { src = w1; dst = dstws + 262144; blk -= 128; }
    else                { src = w2; dst = dstws + 393216; blk -= 192; }
    int idx = (blk * 256 + threadIdx.x) * 8;
    float4 f0 = *(const float4*)(src + idx), f1 = *(const float4*)(src + idx + 4);
    *(bf16x8*)(dst + idx) = pack8(f0, f1);
}

// ---------------- kernel A: K/V proj + per-block KV/Ksum partials ----------------
// grid 1024 = 8 b x 128 blocks (32 src rows). 512 thr = 8 waves; wave w = head w.
// LDS 32KB -> up to 4 blocks/CU if VGPR <= 64 (launch_bounds kept at 4 to avoid spills - R4 lesson).
__global__ __launch_bounds__(512, 4) void kA(const float* __restrict__ src,
                                             const short* __restrict__ wk, const short* __restrict__ wv,
                                             short* __restrict__ kv_part, float* __restrict__ ksum_part) {
    __shared__ char lds[32768];   // phase1: xs[32][256] bf16 swz (16KB); phase3: per-wave kT/vT 4KB x8
    int t = threadIdx.x, lane = t & 63, w = t >> 6, r16 = lane & 15, g = lane >> 4;
    int b = blockIdx.x >> 7, blk = blockIdx.x & 127;
    const float* S = src + ((size_t)b * SEQ + blk * 32) * DM;
#pragma unroll
    for (int i = 0; i < 2; i++) {
        int chunk = t + i * 512, row = chunk >> 5, c8 = chunk & 31;
        const float* p = S + row * DM + c8 * 8;
        float4 f0 = *(const float4*)p, f1 = *(const float4*)(p + 4);
        int by = (row * 512 + c8 * 16) ^ ((row & 7) << 4);
        *(bf16x8*)(lds + by) = pack8(f0, f1);
    }
    __syncthreads();
    f32x4 zz = {0.f, 0.f, 0.f, 0.f};
    f32x4 ak[2][2], av[2][2];
#pragma unroll
    for (int mi = 0; mi < 2; mi++)
#pragma unroll
        for (int ni = 0; ni < 2; ni++) { ak[mi][ni] = zz; av[mi][ni] = zz; }
#pragma unroll
    for (int kt = 0; kt < 8; kt++) {
        bf16x8 A[2];
#pragma unroll
        for (int mi = 0; mi < 2; mi++) {
            int row = mi * 16 + r16;
            A[mi] = *(const bf16x8*)(lds + ((row * 512 + (kt * 32 + g * 8) * 2) ^ ((row & 7) << 4)));
        }
#pragma unroll
        for (int ni = 0; ni < 2; ni++) {
            int n = w * 32 + ni * 16 + r16;
            bf16x8 Bk = *(const bf16x8*)(wk + n * DM + kt * 32 + g * 8);
            bf16x8 Bv = *(const bf16x8*)(wv + n * DM + kt * 32 + g * 8);
#pragma unroll
            for (int mi = 0; mi < 2; mi++) {
                ak[mi][ni] = MFMA16(A[mi], Bk, ak[mi][ni]);
                av[mi][ni] = MFMA16(A[mi], Bv, av[mi][ni]);
            }
        }
    }
    __syncthreads();   // xs reads done before kT/vT overwrite
    // elu(k)+1, ksum partials, per-wave transposed tiles kT/vT [32 feat][32 s]
    char* kT = lds + w * 4096;
    char* vT = kT + 2048;
    float ksp[2] = {0.f, 0.f};
#pragma unroll
    for (int mi = 0; mi < 2; mi++)
#pragma unroll
        for (int ni = 0; ni < 2; ni++)
#pragma unroll
            for (int j = 0; j < 4; j++) {
                float q = ak[mi][ni][j];
                float e = q > 0.f ? q + 1.f : __expf(q);
                ksp[ni] += e;
                int srow = mi * 16 + g * 4 + j, feat = ni * 16 + r16;
                int by = feat * 64 + srow * 2;
                *(short*)(kT + by) = f2bf(e);
                *(short*)(vT + by) = f2bf(av[mi][ni][j]);
            }
    __syncthreads();
    // KVT[v][d] = sum_s V[s][v] * K[s][d]  (per wave, own head; K-dim = 32 = one MFMA)
    f32x4 kv[2][2];
#pragma unroll
    for (int vi = 0; vi < 2; vi++)
#pragma unroll
        for (int di = 0; di < 2; di++) kv[vi][di] = zz;
    {
        bf16x8 Af[2], Bf[2];
#pragma unroll
        for (int vi = 0; vi < 2; vi++) {
            int row = vi * 16 + r16;
            Af[vi] = *(const bf16x8*)(vT + row * 64 + g * 16);
            Bf[vi] = *(const bf16x8*)(kT + row * 64 + g * 16);
        }
#pragma unroll
        for (int vi = 0; vi < 2; vi++)
#pragma unroll
            for (int di = 0; di < 2; di++) kv[vi][di] = MFMA16(Af[vi], Bf[di], kv[vi][di]);
    }
    short* kvp = kv_part + ((size_t)(b * 128 + blk) * 8 + w) * 1024;
#pragma unroll
    for (int vi = 0; vi < 2; vi++)
#pragma unroll
        for (int di = 0; di < 2; di++)
#pragma unroll
            for (int j = 0; j < 4; j++) {
                int v = vi * 16 + g * 4 + j, d = di * 16 + r16;
                kvp[v * 32 + d] = f2bf(kv[vi][di][j]);
            }
#pragma unroll
    for (int ni = 0; ni < 2; ni++) {
        ksp[ni] += __shfl_xor(ksp[ni], 16);
        ksp[ni] += __shfl_xor(ksp[ni], 32);
    }
    if (lane < 16) {
        float* kp = ksum_part + (size_t)(b * 128 + blk) * 256 + w * 32;
#pragma unroll
        for (int ni = 0; ni < 2; ni++) kp[ni * 16 + lane] = ksp[ni];
    }
}

// ---------------- kernel A2: reduce partials ----------------
// grid 256 = b(8) x h(8) x quarter(4), 256 thr. ksum reduced 4-way parallel into ksum4.
__global__ __launch_bounds__(256) void kA2(const short* __restrict__ kv_part, const float* __restrict__ ksum_part,
                                           short* __restrict__ kvt_bf, float* __restrict__ ksum4) {
    int blk = blockIdx.x, t = threadIdx.x;
    int b = blk >> 5, h = (blk >> 2) & 7, q = blk & 3;
    int e = q * 256 + t;
    float s0 = 0.f, s1 = 0.f, s2 = 0.f, s3 = 0.f;
    for (int bk = 0; bk < 128; bk += 4) {
        s0 += bf2f(kv_part[((size_t)(b * 128 + bk) * 8 + h) * 1024 + e]);
        s1 += bf2f(kv_part[((size_t)(b * 128 + bk + 1) * 8 + h) * 1024 + e]);
        s2 += bf2f(kv_part[((size_t)(b * 128 + bk + 2) * 8 + h) * 1024 + e]);
        s3 += bf2f(kv_part[((size_t)(b * 128 + bk + 3) * 8 + h) * 1024 + e]);
    }
    kvt_bf[(size_t)(b * 8 + h) * 1024 + e] = f2bf((s0 + s1) + (s2 + s3));
    if (t < 32) {
        float s = 0.f;
        for (int bk = q * 32; bk < q * 32 + 32; bk++)
            s += ksum_part[(size_t)(b * 128 + bk) * 256 + h * 32 + t];
        ksum4[((b * 8 + h) * 4 + q) * 32 + t] = s;
    }
}

// ---------------- kernel BC: Q proj + attend + merge + LN1 + MLP + LN2 ----------------
// grid 1024 = 8 b x 128 blocks (32 rows). 512 thr = 8 waves. LDS 35KB.
// launch_bounds (512,4): R4's (512,8) forced VGPR=32 -> 365MB scratch spill traffic. 64 VGPR
// (what the allocator picks at bound 4) is exactly the 8-waves/SIMD boundary anyway.
__global__ __launch_bounds__(512, 4) void kBC(const float* __restrict__ x,
                                              const short* __restrict__ wq_bf, const short* __restrict__ wm_bf,
                                              const short* __restrict__ w1_bf, const short* __restrict__ w2_bf,
                                              const short* __restrict__ kvt_bf, const float* __restrict__ ksum4,
                                              const float* __restrict__ g1, const float* __restrict__ b1,
                                              const float* __restrict__ g2, const float* __restrict__ b2,
                                              float* __restrict__ out) {
    __shared__ char lds[35840];
    // xt@0: [32][256] bf16 swz (16KB) -- x, later x1
    // qa@16384: [32][256] bf16 swz (16KB) -- Q, attended, then h-halves
    // red@32768: [32][8][2] f32 (2KB); ksl@34816: [256] f32 (1KB)
    char* xt = lds;
    char* qa = lds + 16384;
    float* red = (float*)(lds + 32768);
    float* ksl = (float*)(lds + 34816);
    int t = threadIdx.x, lane = t & 63, w = t >> 6, r16 = lane & 15, g = lane >> 4;
    int b = blockIdx.x >> 7, lb = blockIdx.x & 127, l0 = lb * 32;
    const float* xb = x + ((size_t)b * SEQ + l0) * DM;
#pragma unroll
    for (int i = 0; i < 2; i++) {
        int chunk = t + i * 512, row = chunk >> 5, c8 = chunk & 31;
        const float* p = xb + row * DM + c8 * 8;
        float4 f0 = *(const float4*)p, f1 = *(const float4*)(p + 4);
        int by = (row * 512 + c8 * 16) ^ ((row & 7) << 4);
        *(bf16x8*)(xt + by) = pack8(f0, f1);
    }
    if (t < 256) {
        int h = t >> 5, d = t & 31;
        const float* kp = ksum4 + (size_t)((b * 8 + h) * 4) * 32 + d;
        ksl[t] = (kp[0] + kp[32]) + (kp[64] + kp[96]);
    }
    __syncthreads();
    f32x4 zz = {0.f, 0.f, 0.f, 0.f};
    // ---- Q projection (wave w -> head w's 32 cols) ----
    f32x4 acc[2][2];
#pragma unroll
    for (int mi = 0; mi < 2; mi++)
#pragma unroll
        for (int ni = 0; ni < 2; ni++) acc[mi][ni] = zz;
#pragma unroll
    for (int kt = 0; kt < 8; kt++) {
        bf16x8 A[2], Bf[2];
#pragma unroll
        for (int mi = 0; mi < 2; mi++) {
            int row = mi * 16 + r16;
            A[mi] = *(const bf16x8*)(xt + ((row * 512 + (kt * 32 + g * 8) * 2) ^ ((row & 7) << 4)));
        }
#pragma unroll
        for (int ni = 0; ni < 2; ni++)
            Bf[ni] = *(const bf16x8*)(wq_bf + (w * 32 + ni * 16 + r16) * DM + kt * 32 + g * 8);
#pragma unroll
        for (int mi = 0; mi < 2; mi++)
#pragma unroll
            for (int ni = 0; ni < 2; ni++) acc[mi][ni] = MFMA16(A[mi], Bf[ni], acc[mi][ni]);
    }
    // elu+1 and Z denominators
    float ks0 = ksl[w * 32 + r16], ks1 = ksl[w * 32 + 16 + r16];
    float Zr[2][4];
#pragma unroll
    for (int mi = 0; mi < 2; mi++)
#pragma unroll
        for (int j = 0; j < 4; j++) {
#pragma unroll
            for (int ni = 0; ni < 2; ni++) {
                float q = acc[mi][ni][j];
                acc[mi][ni][j] = q > 0.f ? q + 1.f : __expf(q);
            }
            float d0 = acc[mi][0][j] * ks0 + acc[mi][1][j] * ks1;
#pragma unroll
            for (int m = 1; m < 16; m <<= 1) d0 += __shfl_xor(d0, m);
            Zr[mi][j] = 1.f / (d0 + 1e-6f);
        }
    // write Q (bf16 swz, wave-private cols)
#pragma unroll
    for (int mi = 0; mi < 2; mi++)
#pragma unroll
        for (int ni = 0; ni < 2; ni++)
#pragma unroll
            for (int j = 0; j < 4; j++) {
                int row = mi * 16 + g * 4 + j, col = w * 32 + ni * 16 + r16;
                *(short*)(qa + ((row * 512 + col * 2) ^ ((row & 7) << 4))) = f2bf(acc[mi][ni][j]);
            }
    // ---- attend (wave-private cols, K-dim=32) ----
    f32x4 at[2][2];
#pragma unroll
    for (int mi = 0; mi < 2; mi++)
#pragma unroll
        for (int vi = 0; vi < 2; vi++) at[mi][vi] = zz;
    {
        bf16x8 A2[2], B2[2];
#pragma unroll
        for (int mi = 0; mi < 2; mi++) {
            int row = mi * 16 + r16, col = w * 32 + g * 8;
            A2[mi] = *(const bf16x8*)(qa + ((row * 512 + col * 2) ^ ((row & 7) << 4)));
        }
        const short* kvb = kvt_bf + (size_t)(b * 8 + w) * 1024;
#pragma unroll
        for (int vi = 0; vi < 2; vi++)
            B2[vi] = *(const bf16x8*)(kvb + (vi * 16 + r16) * 32 + g * 8);
#pragma unroll
        for (int mi = 0; mi < 2; mi++)
#pragma unroll
            for (int vi = 0; vi < 2; vi++) at[mi][vi] = MFMA16(A2[mi], B2[vi], at[mi][vi]);
    }
    // scale by Z, overwrite qa with attended (wave-private cols)
#pragma unroll
    for (int mi = 0; mi < 2; mi++)
#pragma unroll
        for (int vi = 0; vi < 2; vi++)
#pragma unroll
            for (int j = 0; j < 4; j++) {
                int row = mi * 16 + g * 4 + j, col = w * 32 + vi * 16 + r16;
                *(short*)(qa + ((row * 512 + col * 2) ^ ((row & 7) << 4))) = f2bf(at[mi][vi][j] * Zr[mi][j]);
            }
    __syncthreads();   // merge reads all columns
    // ---- merge GEMM ----
    f32x4 am[2][2];
#pragma unroll
    for (int mi = 0; mi < 2; mi++)
#pragma unroll
        for (int ni = 0; ni < 2; ni++) am[mi][ni] = zz;
#pragma unroll
    for (int kt = 0; kt < 8; kt++) {
        bf16x8 A[2], Bf[2];
#pragma unroll
        for (int mi = 0; mi < 2; mi++) {
            int row = mi * 16 + r16;
            A[mi] = *(const bf16x8*)(qa + ((row * 512 + (kt * 32 + g * 8) * 2) ^ ((row & 7) << 4)));
        }
#pragma unroll
        for (int ni = 0; ni < 2; ni++)
            Bf[ni] = *(const bf16x8*)(wm_bf + (w * 32 + ni * 16 + r16) * DM + kt * 32 + g * 8);
#pragma unroll
        for (int mi = 0; mi < 2; mi++)
#pragma unroll
            for (int ni = 0; ni < 2; ni++) am[mi][ni] = MFMA16(A[mi], Bf[ni], am[mi][ni]);
    }
    // LN1 partials
#pragma unroll
    for (int mi = 0; mi < 2; mi++)
#pragma unroll
        for (int j = 0; j < 4; j++) {
            float s = am[mi][0][j] + am[mi][1][j];
            float s2 = am[mi][0][j] * am[mi][0][j] + am[mi][1][j] * am[mi][1][j];
#pragma unroll
            for (int m = 1; m < 16; m <<= 1) { s += __shfl_xor(s, m); s2 += __shfl_xor(s2, m); }
            if (r16 == 0) { int row = mi * 16 + g * 4 + j; red[(row * 8 + w) * 2] = s; red[(row * 8 + w) * 2 + 1] = s2; }
        }
    __syncthreads();
    // x1 = x + LN1(message), in place in xt
    {
        float g1v[2], b1v[2];
#pragma unroll
        for (int ni = 0; ni < 2; ni++) { int col = w * 32 + ni * 16 + r16; g1v[ni] = g1[col]; b1v[ni] = b1[col]; }
#pragma unroll
        for (int mi = 0; mi < 2; mi++)
#pragma unroll
            for (int j = 0; j < 4; j++) {
                int row = mi * 16 + g * 4 + j;
                float mu = 0.f, ex2 = 0.f;
#pragma unroll
                for (int ww = 0; ww < 8; ww++) { mu += red[(row * 8 + ww) * 2]; ex2 += red[(row * 8 + ww) * 2 + 1]; }
                mu *= (1.f / DM); ex2 *= (1.f / DM);
                float rstd = rsqrtf(ex2 - mu * mu + 1e-5f);
#pragma unroll
                for (int ni = 0; ni < 2; ni++) {
                    int col = w * 32 + ni * 16 + r16;
                    int by = (row * 512 + col * 2) ^ ((row & 7) << 4);
                    float xv = bf2f(*(const short*)(xt + by));
                    *(short*)(xt + by) = f2bf(xv + (am[mi][ni][j] - mu) * rstd * g1v[ni] + b1v[ni]);
                }
            }
    }
    __syncthreads();
    // ---- MLP fused in 2 halves of h (qa reused as [32][256] h-tile) ----
    f32x4 a2[2][2];
#pragma unroll
    for (int mi = 0; mi < 2; mi++)
#pragma unroll
        for (int ni = 0; ni < 2; ni++) a2[mi][ni] = zz;
#pragma unroll
    for (int hf = 0; hf < 2; hf++) {
        // GEMM1 half: wave w -> h-cols hf*256 + w*32 + [0,32)
        f32x4 a1[2][2];
#pragma unroll
        for (int mi = 0; mi < 2; mi++)
#pragma unroll
            for (int ni = 0; ni < 2; ni++) a1[mi][ni] = zz;
#pragma unroll
        for (int kt = 0; kt < 8; kt++) {
            bf16x8 A[2], Bf[2];
#pragma unroll
            for (int mi = 0; mi < 2; mi++) {
                int row = mi * 16 + r16;
                A[mi] = *(const bf16x8*)(xt + ((row * 512 + (kt * 32 + g * 8) * 2) ^ ((row & 7) << 4)));
            }
#pragma unroll
            for (int ni = 0; ni < 2; ni++)
                Bf[ni] = *(const bf16x8*)(w1_bf + (hf * 256 + w * 32 + ni * 16 + r16) * DM + kt * 32 + g * 8);
#pragma unroll
            for (int mi = 0; mi < 2; mi++)
#pragma unroll
                for (int ni = 0; ni < 2; ni++) a1[mi][ni] = MFMA16(A[mi], Bf[ni], a1[mi][ni]);
        }
        // relu + write h-half (wave-private cols within [0,256))
#pragma unroll
        for (int mi = 0; mi < 2; mi++)
#pragma unroll
            for (int ni = 0; ni < 2; ni++)
#pragma unroll
                for (int j = 0; j < 4; j++) {
                    float hv = a1[mi][ni][j]; hv = hv > 0.f ? hv : 0.f;
                    int row = mi * 16 + g * 4 + j, col = w * 32 + ni * 16 + r16;
                    *(short*)(qa + ((row * 512 + col * 2) ^ ((row & 7) << 4))) = f2bf(hv);
                }
        __syncthreads();
        // GEMM2 partial over this half's K=256
#pragma unroll
        for (int kt = 0; kt < 8; kt++) {
            bf16x8 A[2], Bf[2];
#pragma unroll
            for (int mi = 0; mi < 2; mi++) {
                int row = mi * 16 + r16;
                A[mi] = *(const bf16x8*)(qa + ((row * 512 + (kt * 32 + g * 8) * 2) ^ ((row & 7) << 4)));
            }
#pragma unroll
            for (int ni = 0; ni < 2; ni++)
                Bf[ni] = *(const bf16x8*)(w2_bf + (w * 32 + ni * 16 + r16) * 512 + hf * 256 + kt * 32 + g * 8);
#pragma unroll
            for (int mi = 0; mi < 2; mi++)
#pragma unroll
                for (int ni = 0; ni < 2; ni++) a2[mi][ni] = MFMA16(A[mi], Bf[ni], a2[mi][ni]);
        }
        __syncthreads();
    }
    // LN2 partials
#pragma unroll
    for (int mi = 0; mi < 2; mi++)
#pragma unroll
        for (int j = 0; j < 4; j++) {
            float s = a2[mi][0][j] + a2[mi][1][j];
            float s2 = a2[mi][0][j] * a2[mi][0][j] + a2[mi][1][j] * a2[mi][1][j];
#pragma unroll
            for (int m = 1; m < 16; m <<= 1) { s += __shfl_xor(s, m); s2 += __shfl_xor(s2, m); }
            if (r16 == 0) { int row = mi * 16 + g * 4 + j; red[(row * 8 + w) * 2] = s; red[(row * 8 + w) * 2 + 1] = s2; }
        }
    __syncthreads();
    // out = x1 + LN2(y)
    {
        float g2v[2], b2v[2];
#pragma unroll
        for (int ni = 0; ni < 2; ni++) { int col = w * 32 + ni * 16 + r16; g2v[ni] = g2[col]; b2v[ni] = b2[col]; }
        float* op = out + ((size_t)b * SEQ + l0) * DM;
#pragma unroll
        for (int mi = 0; mi < 2; mi++)
#pragma unroll
            for (int j = 0; j < 4; j++) {
                int row = mi * 16 + g * 4 + j;
                float mu = 0.f, ex2 = 0.f;
#pragma unroll
                for (int ww = 0; ww < 8; ww++) { mu += red[(row * 8 + ww) * 2]; ex2 += red[(row * 8 + ww) * 2 + 1]; }
                mu *= (1.f / DM); ex2 *= (1.f / DM);
                float rstd = rsqrtf(ex2 - mu * mu + 1e-5f);
#pragma unroll
                for (int ni = 0; ni < 2; ni++) {
                    int col = w * 32 + ni * 16 + r16;
                    float xv = bf2f(*(const short*)(xt + ((row * 512 + col * 2) ^ ((row & 7) << 4))));
                    op[row * DM + col] = xv + (a2[mi][ni][j] - mu) * rstd * g2v[ni] + b2v[ni];
                }
            }
    }
}

extern "C" void kernel_launch(void* const* d_in, const int* in_sizes, int n_in,
                              void* d_out, int out_size, void* d_ws, size_t ws_size,
                              hipStream_t stream) {
    const float* x   = (const float*)d_in[0];
    const float* src = (const float*)d_in[1];
    const float* wq  = (const float*)d_in[2];
    const float* wk  = (const float*)d_in[3];
    const float* wv  = (const float*)d_in[4];
    const float* wm  = (const float*)d_in[5];
    const float* w1  = (const float*)d_in[6];
    const float* w2  = (const float*)d_in[7];
    const float* g1  = (const float*)d_in[8];
    const float* b1  = (const float*)d_in[9];
    const float* g2  = (const float*)d_in[10];
    const float* b2  = (const float*)d_in[11];
    float* out = (float*)d_out;

    char* ws = (char*)d_ws;
    short* w_bf      = (short*)ws;                    // 1,048,576 B
    short* kvt_bf    = (short*)(ws + 1048576);        //   131,072 B
    float* ksum4     = (float*)(ws + 1179648);        //    32,768 B
    short* kv_part   = (short*)(ws + 1212416);        // 16,777,216 B (bf16 partials)
    float* ksum_part = (float*)(ws + 17989632);       //  1,048,576 B  -> total 19.0 MB

    kWconv<<<256, 256, 0, stream>>>(wq, wk, wv, wm, w1, w2, w_bf);
    kA<<<1024, 512, 0, stream>>>(src, w_bf + 65536, w_bf + 131072, kv_part, ksum_part);
    kA2<<<256, 256, 0, stream>>>(kv_part, ksum_part, kvt_bf, ksum4);
    kBC<<<1024, 512, 0, stream>>>(x, w_bf, w_bf + 196608, w_bf + 262144, w_bf + 393216,
                                  kvt_bf, ksum4, g1, b1, g2, b2, out);
}

// Round 6
// 215.575 us; speedup vs baseline: 1.4025x; 1.1985x over previous
//
#include <hip/hip_runtime.h>

#define DM 256
#define SEQ 4096
#define XSTR 528   // xt/qa row stride bytes (132 dwords = 4-bank rotate/row, 2-way = free)
#define KSTR 144   // kA transpose tile row stride bytes (36 dwords = 4-bank rotate)

typedef __attribute__((ext_vector_type(8))) short bf16x8;
typedef __attribute__((ext_vector_type(4))) float f32x4;

#define MFMA16(a, b, c) __builtin_amdgcn_mfma_f32_16x16x32_bf16(a, b, c, 0, 0, 0)

__device__ __forceinline__ short f2bf(float f) {
    union { float f; unsigned u; } c; c.f = f;
    unsigned r = (c.u + 0x7FFFu + ((c.u >> 16) & 1u)) >> 16;   // RNE
    return (short)r;
}
__device__ __forceinline__ float bf2f(short s) {
    union { unsigned u; float f; } c; c.u = ((unsigned)(unsigned short)s) << 16; return c.f;
}
__device__ __forceinline__ bf16x8 pack8(float4 a, float4 b) {
    bf16x8 r;
    r[0] = f2bf(a.x); r[1] = f2bf(a.y); r[2] = f2bf(a.z); r[3] = f2bf(a.w);
    r[4] = f2bf(b.x); r[5] = f2bf(b.y); r[6] = f2bf(b.z); r[7] = f2bf(b.w);
    return r;
}

// ---------------- weight f32 -> bf16 ----------------
// ws shorts: wq@0 wk@65536 wv@131072 wm@196608 w1@262144 w2@393216
__global__ __launch_bounds__(256) void kWconv(const float* __restrict__ wq, const float* __restrict__ wk,
                                              const float* __restrict__ wv, const float* __restrict__ wm,
                                              const float* __restrict__ w1, const float* __restrict__ w2,
                                              short* __restrict__ dstws) {
    int blk = blockIdx.x;
    const float* src; short* dst;
    if (blk < 32)       { src = wq; dst = dstws;          }
    else if (blk < 64)  { src = wk; dst = dstws + 65536;  blk -= 32; }
    else if (blk < 96)  { src = wv; dst = dstws + 131072; blk -= 64; }
    else if (blk < 128) { src = wm; dst = dstws + 196608; blk -= 96; }
    else if (blk < 192) { src = w1; dst = dstws + 262144; blk -= 128; }
    else                { src = w2; dst = dstws + 393216; blk -= 192; }
    int idx = (blk * 256 + threadIdx.x) * 8;
    float4 f0 = *(const float4*)(src + idx), f1 = *(const float4*)(src + idx + 4);
    *(bf16x8*)(dst + idx) = pack8(f0, f1);
}

// ---------------- kernel A: K/V proj + per-block KV/Ksum partials ----------------
// grid 512 = 8 b x 64 blocks (64 src rows). 512 thr = 8 waves; wave w = head w.
// LDS overlay: phase1 xs[64][XSTR] (33.8KB) -> phase3 per-wave kT/vT (9216B x 8 = 73.7KB). 2 blocks/CU.
__global__ __launch_bounds__(512, 4) void kA(const float* __restrict__ src,
                                             const short* __restrict__ wk, const short* __restrict__ wv,
                                             short* __restrict__ kv_part, float* __restrict__ ksum_part) {
    __shared__ char lds[73728];
    int t = threadIdx.x, lane = t & 63, w = t >> 6, r16 = lane & 15, g = lane >> 4;
    int b = blockIdx.x >> 6, blk = blockIdx.x & 63;
    const float* S = src + ((size_t)b * SEQ + blk * 64) * DM;
#pragma unroll
    for (int i = 0; i < 4; i++) {
        int chunk = t + i * 512, row = chunk >> 5, c8 = chunk & 31;
        const float* p = S + row * DM + c8 * 8;
        float4 f0 = *(const float4*)p, f1 = *(const float4*)(p + 4);
        *(bf16x8*)(lds + row * XSTR + c8 * 16) = pack8(f0, f1);
    }
    __syncthreads();
    f32x4 zz = {0.f, 0.f, 0.f, 0.f};
    f32x4 ak[4][2], av[4][2];
#pragma unroll
    for (int mi = 0; mi < 4; mi++)
#pragma unroll
        for (int ni = 0; ni < 2; ni++) { ak[mi][ni] = zz; av[mi][ni] = zz; }
    // precomputed bases; kt-loop addresses fold to offset immediates
    const char* aB0 = lds + r16 * XSTR + g * 16;
    const short* wkB0 = wk + (w * 32 + r16) * DM + g * 8;
    const short* wvB0 = wv + (w * 32 + r16) * DM + g * 8;
#pragma unroll
    for (int kt = 0; kt < 8; kt++) {
        bf16x8 A[4];
#pragma unroll
        for (int mi = 0; mi < 4; mi++)
            A[mi] = *(const bf16x8*)(aB0 + mi * (16 * XSTR) + kt * 64);
#pragma unroll
        for (int ni = 0; ni < 2; ni++) {
            bf16x8 Bk = *(const bf16x8*)(wkB0 + ni * (16 * DM) + kt * 32);
            bf16x8 Bv = *(const bf16x8*)(wvB0 + ni * (16 * DM) + kt * 32);
#pragma unroll
            for (int mi = 0; mi < 4; mi++) {
                ak[mi][ni] = MFMA16(A[mi], Bk, ak[mi][ni]);
                av[mi][ni] = MFMA16(A[mi], Bv, av[mi][ni]);
            }
        }
    }
    __syncthreads();   // xs reads done before kT/vT overwrite
    // elu(k)+1, ksum partials, per-wave transposed tiles kT/vT [32 feat][64 s]
    char* kT = lds + w * 9216;
    char* vT = kT + 4608;
    float ksp[2] = {0.f, 0.f};
#pragma unroll
    for (int mi = 0; mi < 4; mi++)
#pragma unroll
        for (int ni = 0; ni < 2; ni++)
#pragma unroll
            for (int j = 0; j < 4; j++) {
                float q = ak[mi][ni][j];
                float e = q > 0.f ? q + 1.f : __expf(q);
                ksp[ni] += e;
                int srow = mi * 16 + g * 4 + j, feat = ni * 16 + r16;
                int by = feat * KSTR + srow * 2;
                *(short*)(kT + by) = f2bf(e);
                *(short*)(vT + by) = f2bf(av[mi][ni][j]);
            }
    __syncthreads();
    // KVT[v][d] = sum_s V[s][v] * K[s][d]  (per wave, own head; K-dim = 64 = 2 MFMA steps)
    f32x4 kv[2][2];
#pragma unroll
    for (int vi = 0; vi < 2; vi++)
#pragma unroll
        for (int di = 0; di < 2; di++) kv[vi][di] = zz;
    {
        const char* vB = vT + r16 * KSTR + g * 16;
        const char* kB = kT + r16 * KSTR + g * 16;
#pragma unroll
        for (int st = 0; st < 2; st++) {
            bf16x8 Af[2], Bf[2];
#pragma unroll
            for (int vi = 0; vi < 2; vi++) {
                Af[vi] = *(const bf16x8*)(vB + vi * (16 * KSTR) + st * 64);
                Bf[vi] = *(const bf16x8*)(kB + vi * (16 * KSTR) + st * 64);
            }
#pragma unroll
            for (int vi = 0; vi < 2; vi++)
#pragma unroll
                for (int di = 0; di < 2; di++) kv[vi][di] = MFMA16(Af[vi], Bf[di], kv[vi][di]);
        }
    }
    short* kvp = kv_part + ((size_t)(b * 64 + blk) * 8 + w) * 1024;
#pragma unroll
    for (int vi = 0; vi < 2; vi++)
#pragma unroll
        for (int di = 0; di < 2; di++)
#pragma unroll
            for (int j = 0; j < 4; j++) {
                int v = vi * 16 + g * 4 + j, d = di * 16 + r16;
                kvp[v * 32 + d] = f2bf(kv[vi][di][j]);
            }
#pragma unroll
    for (int ni = 0; ni < 2; ni++) {
        ksp[ni] += __shfl_xor(ksp[ni], 16);
        ksp[ni] += __shfl_xor(ksp[ni], 32);
    }
    if (lane < 16) {
        float* kp = ksum_part + (size_t)(b * 64 + blk) * 256 + w * 32;
#pragma unroll
        for (int ni = 0; ni < 2; ni++) kp[ni * 16 + lane] = ksp[ni];
    }
}

// ---------------- kernel A2: reduce partials ----------------
// grid 256 = b(8) x h(8) x quarter(4), 256 thr.
__global__ __launch_bounds__(256) void kA2(const short* __restrict__ kv_part, const float* __restrict__ ksum_part,
                                           short* __restrict__ kvt_bf, float* __restrict__ ksum4) {
    int blk = blockIdx.x, t = threadIdx.x;
    int b = blk >> 5, h = (blk >> 2) & 7, q = blk & 3;
    int e = q * 256 + t;
    float s0 = 0.f, s1 = 0.f, s2 = 0.f, s3 = 0.f;
    for (int bk = 0; bk < 64; bk += 4) {
        s0 += bf2f(kv_part[((size_t)(b * 64 + bk) * 8 + h) * 1024 + e]);
        s1 += bf2f(kv_part[((size_t)(b * 64 + bk + 1) * 8 + h) * 1024 + e]);
        s2 += bf2f(kv_part[((size_t)(b * 64 + bk + 2) * 8 + h) * 1024 + e]);
        s3 += bf2f(kv_part[((size_t)(b * 64 + bk + 3) * 8 + h) * 1024 + e]);
    }
    kvt_bf[(size_t)(b * 8 + h) * 1024 + e] = f2bf((s0 + s1) + (s2 + s3));
    if (t < 32) {
        float s = 0.f;
        for (int bk = q * 16; bk < q * 16 + 16; bk++)
            s += ksum_part[(size_t)(b * 64 + bk) * 256 + h * 32 + t];
        ksum4[((b * 8 + h) * 4 + q) * 32 + t] = s;
    }
}

// ---------------- kernel BC: Q proj + attend + merge + LN1 + MLP + LN2 ----------------
// grid 512 = 8 b x 64 blocks (64 rows). 512 thr = 8 waves. LDS 71KB -> 2 blocks/CU.
__global__ __launch_bounds__(512, 4) void kBC(const float* __restrict__ x,
                                              const short* __restrict__ wq_bf, const short* __restrict__ wm_bf,
                                              const short* __restrict__ w1_bf, const short* __restrict__ w2_bf,
                                              const short* __restrict__ kvt_bf, const float* __restrict__ ksum4,
                                              const float* __restrict__ g1, const float* __restrict__ b1,
                                              const float* __restrict__ g2, const float* __restrict__ b2,
                                              float* __restrict__ out) {
    __shared__ char lds[72704];
    // xt@0: [64][XSTR] bf16 (33792B) -- x, later x1
    // qa@33792: [64][XSTR] -- Q, attended, then h-halves
    // red@67584: [64][8][2] f32 (4KB); ksl@71680: [256] f32 (1KB)
    char* xt = lds;
    char* qa = lds + 33792;
    float* red = (float*)(lds + 67584);
    float* ksl = (float*)(lds + 71680);
    int t = threadIdx.x, lane = t & 63, w = t >> 6, r16 = lane & 15, g = lane >> 4;
    int b = blockIdx.x >> 6, lb = blockIdx.x & 63, l0 = lb * 64;
    const float* xb = x + ((size_t)b * SEQ + l0) * DM;
#pragma unroll
    for (int i = 0; i < 4; i++) {
        int chunk = t + i * 512, row = chunk >> 5, c8 = chunk & 31;
        const float* p = xb + row * DM + c8 * 8;
        float4 f0 = *(const float4*)p, f1 = *(const float4*)(p + 4);
        *(bf16x8*)(xt + row * XSTR + c8 * 16) = pack8(f0, f1);
    }
    if (t < 256) {
        int h = t >> 5, d = t & 31;
        const float* kp = ksum4 + (size_t)((b * 8 + h) * 4) * 32 + d;
        ksl[t] = (kp[0] + kp[32]) + (kp[64] + kp[96]);
    }
    __syncthreads();
    f32x4 zz = {0.f, 0.f, 0.f, 0.f};
    const char* aXB = xt + r16 * XSTR + g * 16;   // A-frag base in xt
    const char* aQB = qa + r16 * XSTR + g * 16;   // A-frag base in qa
    // ---- Q projection (wave w -> head w's 32 cols) ----
    f32x4 acc[4][2];
#pragma unroll
    for (int mi = 0; mi < 4; mi++)
#pragma unroll
        for (int ni = 0; ni < 2; ni++) acc[mi][ni] = zz;
    {
        const short* wqB = wq_bf + (w * 32 + r16) * DM + g * 8;
#pragma unroll
        for (int kt = 0; kt < 8; kt++) {
            bf16x8 A[4], Bf[2];
#pragma unroll
            for (int mi = 0; mi < 4; mi++)
                A[mi] = *(const bf16x8*)(aXB + mi * (16 * XSTR) + kt * 64);
#pragma unroll
            for (int ni = 0; ni < 2; ni++)
                Bf[ni] = *(const bf16x8*)(wqB + ni * (16 * DM) + kt * 32);
#pragma unroll
            for (int mi = 0; mi < 4; mi++)
#pragma unroll
                for (int ni = 0; ni < 2; ni++) acc[mi][ni] = MFMA16(A[mi], Bf[ni], acc[mi][ni]);
        }
    }
    // elu+1 and Z denominators
    float ks0 = ksl[w * 32 + r16], ks1 = ksl[w * 32 + 16 + r16];
    float Zr[4][4];
#pragma unroll
    for (int mi = 0; mi < 4; mi++)
#pragma unroll
        for (int j = 0; j < 4; j++) {
#pragma unroll
            for (int ni = 0; ni < 2; ni++) {
                float q = acc[mi][ni][j];
                acc[mi][ni][j] = q > 0.f ? q + 1.f : __expf(q);
            }
            float d0 = acc[mi][0][j] * ks0 + acc[mi][1][j] * ks1;
#pragma unroll
            for (int m = 1; m < 16; m <<= 1) d0 += __shfl_xor(d0, m);
            Zr[mi][j] = 1.f / (d0 + 1e-6f);
        }
    // write Q (wave-private cols)
#pragma unroll
    for (int mi = 0; mi < 4; mi++)
#pragma unroll
        for (int ni = 0; ni < 2; ni++)
#pragma unroll
            for (int j = 0; j < 4; j++) {
                int row = mi * 16 + g * 4 + j, col = w * 32 + ni * 16 + r16;
                *(short*)(qa + row * XSTR + col * 2) = f2bf(acc[mi][ni][j]);
            }
    // ---- attend (wave-private cols, K-dim=32) ----
    f32x4 at[4][2];
#pragma unroll
    for (int mi = 0; mi < 4; mi++)
#pragma unroll
        for (int vi = 0; vi < 2; vi++) at[mi][vi] = zz;
    {
        bf16x8 A2[4], B2[2];
#pragma unroll
        for (int mi = 0; mi < 4; mi++)
            A2[mi] = *(const bf16x8*)(qa + (mi * 16 + r16) * XSTR + (w * 32 + g * 8) * 2);
        const short* kvb = kvt_bf + (size_t)(b * 8 + w) * 1024;
#pragma unroll
        for (int vi = 0; vi < 2; vi++)
            B2[vi] = *(const bf16x8*)(kvb + (vi * 16 + r16) * 32 + g * 8);
#pragma unroll
        for (int mi = 0; mi < 4; mi++)
#pragma unroll
            for (int vi = 0; vi < 2; vi++) at[mi][vi] = MFMA16(A2[mi], B2[vi], at[mi][vi]);
    }
    // scale by Z, overwrite qa with attended (wave-private cols)
#pragma unroll
    for (int mi = 0; mi < 4; mi++)
#pragma unroll
        for (int vi = 0; vi < 2; vi++)
#pragma unroll
            for (int j = 0; j < 4; j++) {
                int row = mi * 16 + g * 4 + j, col = w * 32 + vi * 16 + r16;
                *(short*)(qa + row * XSTR + col * 2) = f2bf(at[mi][vi][j] * Zr[mi][j]);
            }
    __syncthreads();   // merge reads all columns
    // ---- merge GEMM ----
    f32x4 am[4][2];
#pragma unroll
    for (int mi = 0; mi < 4; mi++)
#pragma unroll
        for (int ni = 0; ni < 2; ni++) am[mi][ni] = zz;
    {
        const short* wmB = wm_bf + (w * 32 + r16) * DM + g * 8;
#pragma unroll
        for (int kt = 0; kt < 8; kt++) {
            bf16x8 A[4], Bf[2];
#pragma unroll
            for (int mi = 0; mi < 4; mi++)
                A[mi] = *(const bf16x8*)(aQB + mi * (16 * XSTR) + kt * 64);
#pragma unroll
            for (int ni = 0; ni < 2; ni++)
                Bf[ni] = *(const bf16x8*)(wmB + ni * (16 * DM) + kt * 32);
#pragma unroll
            for (int mi = 0; mi < 4; mi++)
#pragma unroll
                for (int ni = 0; ni < 2; ni++) am[mi][ni] = MFMA16(A[mi], Bf[ni], am[mi][ni]);
        }
    }
    // LN1 partials
#pragma unroll
    for (int mi = 0; mi < 4; mi++)
#pragma unroll
        for (int j = 0; j < 4; j++) {
            float s = am[mi][0][j] + am[mi][1][j];
            float s2 = am[mi][0][j] * am[mi][0][j] + am[mi][1][j] * am[mi][1][j];
#pragma unroll
            for (int m = 1; m < 16; m <<= 1) { s += __shfl_xor(s, m); s2 += __shfl_xor(s2, m); }
            if (r16 == 0) { int row = mi * 16 + g * 4 + j; red[(row * 8 + w) * 2] = s; red[(row * 8 + w) * 2 + 1] = s2; }
        }
    __syncthreads();
    // x1 = x + LN1(message), in place in xt
    {
        float g1v[2], b1v[2];
#pragma unroll
        for (int ni = 0; ni < 2; ni++) { int col = w * 32 + ni * 16 + r16; g1v[ni] = g1[col]; b1v[ni] = b1[col]; }
#pragma unroll
        for (int mi = 0; mi < 4; mi++)
#pragma unroll
            for (int j = 0; j < 4; j++) {
                int row = mi * 16 + g * 4 + j;
                float mu = 0.f, ex2 = 0.f;
#pragma unroll
                for (int ww = 0; ww < 8; ww++) { mu += red[(row * 8 + ww) * 2]; ex2 += red[(row * 8 + ww) * 2 + 1]; }
                mu *= (1.f / DM); ex2 *= (1.f / DM);
                float rstd = rsqrtf(ex2 - mu * mu + 1e-5f);
#pragma unroll
                for (int ni = 0; ni < 2; ni++) {
                    int col = w * 32 + ni * 16 + r16;
                    char* bp = xt + row * XSTR + col * 2;
                    float xv = bf2f(*(const short*)bp);
                    *(short*)bp = f2bf(xv + (am[mi][ni][j] - mu) * rstd * g1v[ni] + b1v[ni]);
                }
            }
    }
    __syncthreads();
    // ---- MLP fused in 2 halves of h (qa reused as [64][256] h-tile) ----
    f32x4 a2[4][2];
#pragma unroll
    for (int mi = 0; mi < 4; mi++)
#pragma unroll
        for (int ni = 0; ni < 2; ni++) a2[mi][ni] = zz;
#pragma unroll
    for (int hf = 0; hf < 2; hf++) {
        // GEMM1 half: wave w -> h-cols hf*256 + w*32 + [0,32)
        f32x4 a1[4][2];
#pragma unroll
        for (int mi = 0; mi < 4; mi++)
#pragma unroll
            for (int ni = 0; ni < 2; ni++) a1[mi][ni] = zz;
        {
            const short* w1B = w1_bf + (hf * 256 + w * 32 + r16) * DM + g * 8;
#pragma unroll
            for (int kt = 0; kt < 8; kt++) {
                bf16x8 A[4], Bf[2];
#pragma unroll
                for (int mi = 0; mi < 4; mi++)
                    A[mi] = *(const bf16x8*)(aXB + mi * (16 * XSTR) + kt * 64);
#pragma unroll
                for (int ni = 0; ni < 2; ni++)
                    Bf[ni] = *(const bf16x8*)(w1B + ni * (16 * DM) + kt * 32);
#pragma unroll
                for (int mi = 0; mi < 4; mi++)
#pragma unroll
                    for (int ni = 0; ni < 2; ni++) a1[mi][ni] = MFMA16(A[mi], Bf[ni], a1[mi][ni]);
            }
        }
        // relu + write h-half (wave-private cols within [0,256))
#pragma unroll
        for (int mi = 0; mi < 4; mi++)
#pragma unroll
            for (int ni = 0; ni < 2; ni++)
#pragma unroll
                for (int j = 0; j < 4; j++) {
                    float hv = a1[mi][ni][j]; hv = hv > 0.f ? hv : 0.f;
                    int row = mi * 16 + g * 4 + j, col = w * 32 + ni * 16 + r16;
                    *(short*)(qa + row * XSTR + col * 2) = f2bf(hv);
                }
        __syncthreads();
        // GEMM2 partial over this half's K=256
        {
            const short* w2B = w2_bf + (w * 32 + r16) * 512 + hf * 256 + g * 8;
#pragma unroll
            for (int kt = 0; kt < 8; kt++) {
                bf16x8 A[4], Bf[2];
#pragma unroll
                for (int mi = 0; mi < 4; mi++)
                    A[mi] = *(const bf16x8*)(aQB + mi * (16 * XSTR) + kt * 64);
#pragma unroll
                for (int ni = 0; ni < 2; ni++)
                    Bf[ni] = *(const bf16x8*)(w2B + ni * (16 * 512) + kt * 32);
#pragma unroll
                for (int mi = 0; mi < 4; mi++)
#pragma unroll
                    for (int ni = 0; ni < 2; ni++) a2[mi][ni] = MFMA16(A[mi], Bf[ni], a2[mi][ni]);
            }
        }
        __syncthreads();
    }
    // LN2 partials
#pragma unroll
    for (int mi = 0; mi < 4; mi++)
#pragma unroll
        for (int j = 0; j < 4; j++) {
            float s = a2[mi][0][j] + a2[mi][1][j];
            float s2 = a2[mi][0][j] * a2[mi][0][j] + a2[mi][1][j] * a2[mi][1][j];
#pragma unroll
            for (int m = 1; m < 16; m <<= 1) { s += __shfl_xor(s, m); s2 += __shfl_xor(s2, m); }
            if (r16 == 0) { int row = mi * 16 + g * 4 + j; red[(row * 8 + w) * 2] = s; red[(row * 8 + w) * 2 + 1] = s2; }
        }
    __syncthreads();
    // out = x1 + LN2(y)
    {
        float g2v[2], b2v[2];
#pragma unroll
        for (int ni = 0; ni < 2; ni++) { int col = w * 32 + ni * 16 + r16; g2v[ni] = g2[col]; b2v[ni] = b2[col]; }
        float* op = out + ((size_t)b * SEQ + l0) * DM;
#pragma unroll
        for (int mi = 0; mi < 4; mi++)
#pragma unroll
            for (int j = 0; j < 4; j++) {
                int row = mi * 16 + g * 4 + j;
                float mu = 0.f, ex2 = 0.f;
#pragma unroll
                for (int ww = 0; ww < 8; ww++) { mu += red[(row * 8 + ww) * 2]; ex2 += red[(row * 8 + ww) * 2 + 1]; }
                mu *= (1.f / DM); ex2 *= (1.f / DM);
                float rstd = rsqrtf(ex2 - mu * mu + 1e-5f);
#pragma unroll
                for (int ni = 0; ni < 2; ni++) {
                    int col = w * 32 + ni * 16 + r16;
                    float xv = bf2f(*(const short*)(xt + row * XSTR + col * 2));
                    op[row * DM + col] = xv + (a2[mi][ni][j] - mu) * rstd * g2v[ni] + b2v[ni];
                }
            }
    }
}

extern "C" void kernel_launch(void* const* d_in, const int* in_sizes, int n_in,
                              void* d_out, int out_size, void* d_ws, size_t ws_size,
                              hipStream_t stream) {
    const float* x   = (const float*)d_in[0];
    const float* src = (const float*)d_in[1];
    const float* wq  = (const float*)d_in[2];
    const float* wk  = (const float*)d_in[3];
    const float* wv  = (const float*)d_in[4];
    const float* wm  = (const float*)d_in[5];
    const float* w1  = (const float*)d_in[6];
    const float* w2  = (const float*)d_in[7];
    const float* g1  = (const float*)d_in[8];
    const float* b1  = (const float*)d_in[9];
    const float* g2  = (const float*)d_in[10];
    const float* b2  = (const float*)d_in[11];
    float* out = (float*)d_out;

    char* ws = (char*)d_ws;
    short* w_bf      = (short*)ws;                    // 1,048,576 B
    short* kvt_bf    = (short*)(ws + 1048576);        //   131,072 B
    float* ksum4     = (float*)(ws + 1179648);        //    32,768 B
    short* kv_part   = (short*)(ws + 1212416);        //  8,388,608 B (bf16 partials)
    float* ksum_part = (float*)(ws + 9601024);        //    524,288 B  -> total ~10.1 MB

    kWconv<<<256, 256, 0, stream>>>(wq, wk, wv, wm, w1, w2, w_bf);
    kA<<<512, 512, 0, stream>>>(src, w_bf + 65536, w_bf + 131072, kv_part, ksum_part);
    kA2<<<256, 256, 0, stream>>>(kv_part, ksum_part, kvt_bf, ksum4);
    kBC<<<512, 512, 0, stream>>>(x, w_bf, w_bf + 196608, w_bf + 262144, w_bf + 393216,
                                 kvt_bf, ksum4, g1, b1, g2, b2, out);
}